// Round 16
// baseline (57.073 us; speedup 1.0000x reference)
//
#include <hip/hip_runtime.h>

typedef float f32x4 __attribute__((ext_vector_type(4)));
typedef __bf16 bf16x8 __attribute__((ext_vector_type(8)));
typedef unsigned short u16x8 __attribute__((ext_vector_type(8)));
typedef unsigned u32x2 __attribute__((ext_vector_type(2)));

#define NB 4
#define NH 16
#define TT 4096
#define DD 64
#define LOG2E 1.4426950408889634f
#define QSCALE (LOG2E * 0.125f)   // (1/sqrt(64)) * log2(e)
#define NEGB (-1.5e9f)            // large-negative (log2 domain); exp2 -> 0

__device__ __forceinline__ unsigned cvt_pk_bf16(float a, float b) {
  unsigned r;
  asm("v_cvt_pk_bf16_f32 %0, %1, %2" : "=v"(r) : "v"(a), "v"(b));
  return r;   // lo16 = bf16(a), hi16 = bf16(b)  (RNE)
}
__device__ __forceinline__ float exp2_hw(float x) {
  float r;
  asm("v_exp_f32 %0, %1" : "=v"(r) : "v"(x));
  return r;
}
__device__ __forceinline__ float max3f(float a, float b, float c) {
  float r;
  asm("v_max3_f32 %0, %1, %2, %3" : "=v"(r) : "v"(a), "v"(b), "v"(c));
  return r;
}

// Barrier that waits ONLY on LDS (lgkmcnt), NOT on outstanding global loads.
// __syncthreads() would emit s_waitcnt vmcnt(0) and drain the async V loads.
__device__ __forceinline__ void lds_barrier() {
  __builtin_amdgcn_sched_barrier(0);
  asm volatile("s_waitcnt lgkmcnt(0)" ::: "memory");
  __builtin_amdgcn_s_barrier();
  __builtin_amdgcn_sched_barrier(0);
}

// K tile [256][64] u16 row-major, XOR swizzle for b128 reads at row-stride 128B.
__device__ __forceinline__ int kswz(int key, int d) {
  return ((key << 6) + d) ^ ((key & 7) << 3);
}
// V^T tile [64][256] u16, slot-permuted within 32-key chunks so one lane's 8
// PV-B keys {32c+16hi+4g+r} are ONE contiguous 16B chunk in jj=r+4*hi order:
//   u16 slot within chunk = (key&3) | ((key>>4)&1)<<2
//   16B-chunk index c16(key) = (key>>5)*4 + ((key>>2)&3), swizzled by d.
__device__ __forceinline__ int cswz(int d, int c16) {
  return c16 ^ (d & 7) ^ ((d >> 3) & 7);
}

__global__ __launch_bounds__(512, 4) void swa_fwd(
    const float* __restrict__ Qg, const float* __restrict__ Kg,
    const float* __restrict__ Vg, const float* __restrict__ Mg,
    float* __restrict__ Og) {
  // 65.5 KiB static LDS -> 2 blocks/CU; 8 waves/block -> 4 waves/SIMD (128-reg cap).
  __shared__ unsigned short khs[256 * 64];   // 32 KiB  K  (bf16, kswz)
  __shared__ unsigned short vts[64 * 256];   // 32 KiB  V^T (bf16, slot+cswz)
  __shared__ float bs[256];                  // 1 KiB   bias (mask*log2e / NEGB)

  // XCD-bijective swizzle: 2048 blocks, 8 XCDs, contiguous work per XCD.
  const int bid = blockIdx.x;
  const int flat = (bid & 7) * 256 + (bid >> 3);
  const int i = flat & 31;        // q-block
  const int bh = flat >> 5;       // b*NH + h
  const int b = bh >> 4;

  const int t = threadIdx.x;      // 0..511
  const int lane = t & 63;
  const int wid = t >> 6;         // 0..7
  const int lr = lane & 15;
  const int g = lane >> 4;

  const size_t base = (size_t)bh * (TT * DD);
  const float* Qb = Qg + base;
  const float* Kb = Kg + base;
  const float* Vb = Vg + base;
  const float* Mb = Mg + (size_t)b * TT;
  const int j0 = i * 128 - 128;           // window start (may be -128 for i==0)
  const int qrow0 = i * 128 + wid * 16;   // this wave's 16 rows

  const int dg = (t & 7) * 8;     // 8 consecutive d per thread
  const int rowt = t >> 3;        // K staging: 64 keys per iter
  const int kb = (t >> 3) * 4;    // V staging: 4 consecutive keys per thread

  // ---- issue order matters for vmcnt: K first, then Q, mask, V LAST.
  // Every load below is executed by EVERY wave (no wave-asymmetric vmcnt).
  f32x4 ka[4][2];
#pragma unroll
  for (int it = 0; it < 4; ++it) {
    int j = j0 + it * 64 + rowt;
    j = j < 0 ? 0 : j;            // clamp; invalid keys masked via bias later
    const float* ks = Kb + (size_t)j * DD + dg;
    ka[it][0] = *(const f32x4*)ks;
    ka[it][1] = *(const f32x4*)(ks + 4);
  }
  f32x4 qraw[2][2];
#pragma unroll
  for (int s = 0; s < 2; ++s) {
    const float* qp = Qb + (size_t)(qrow0 + lr) * DD + s * 32 + g * 8;
    qraw[s][0] = *(const f32x4*)qp;
    qraw[s][1] = *(const f32x4*)(qp + 4);
  }
  // mask row: ALL waves load the same 256 entries (4/lane), clamped address.
  const int jm = j0 + (lane << 2);
  const int jmc = jm < 0 ? 0 : jm;
  f32x4 mrow = *(const f32x4*)(Mb + jmc);
  // V issued LAST; stays in flight through QK + softmax (no vmcnt(0) barrier).
  f32x4 va[4][2];
#pragma unroll
  for (int k = 0; k < 4; ++k) {
    int j = j0 + kb + k;
    j = j < 0 ? 0 : j;
    const float* vs = Vb + (size_t)j * DD + dg;
    va[k][0] = *(const f32x4*)vs;
    va[k][1] = *(const f32x4*)(vs + 4);
  }

  // ---- convert + write K (b128, swizzled); waits only on K loads ----
#pragma unroll
  for (int it = 0; it < 4; ++it) {
    int key = it * 64 + rowt;
    union { u16x8 v; unsigned w[4]; } hh;
    hh.w[0] = cvt_pk_bf16(ka[it][0][0], ka[it][0][1]);
    hh.w[1] = cvt_pk_bf16(ka[it][0][2], ka[it][0][3]);
    hh.w[2] = cvt_pk_bf16(ka[it][1][0], ka[it][1][1]);
    hh.w[3] = cvt_pk_bf16(ka[it][1][2], ka[it][1][3]);
    *(u16x8*)(khs + kswz(key, dg)) = hh.v;
  }

  // ---- bias commit: ALL waves write identical values (benign WW race) ----
  {
    f32x4 bb;
    if (jm >= 0) {
      bb = mrow * LOG2E;
    } else {
      bb = (f32x4){NEGB, NEGB, NEGB, NEGB};
    }
    *(f32x4*)(bs + (lane << 2)) = bb;
  }

  // ---- Q fragments: plain bf16 of q * (log2e/8) ----
  bf16x8 qb[2];
#pragma unroll
  for (int s = 0; s < 2; ++s) {
    union { unsigned w[4]; bf16x8 v; } H;
    H.w[0] = cvt_pk_bf16(qraw[s][0][0] * QSCALE, qraw[s][0][1] * QSCALE);
    H.w[1] = cvt_pk_bf16(qraw[s][0][2] * QSCALE, qraw[s][0][3] * QSCALE);
    H.w[2] = cvt_pk_bf16(qraw[s][1][0] * QSCALE, qraw[s][1][1] * QSCALE);
    H.w[3] = cvt_pk_bf16(qraw[s][1][2] * QSCALE, qraw[s][1][3] * QSCALE);
    qb[s] = H.v;
  }

  lds_barrier();   // barrier 1: khs + bias visible; V loads STILL IN FLIGHT

  // ---- QK: acc preloaded with bias; S^T = K * Q^T accumulates on top. ----
  // lane value (mt,r): key = mt*16 + 4g + r ; qrow = lr
  f32x4 acc[16];
#pragma unroll
  for (int mt = 0; mt < 16; ++mt)
    acc[mt] = *(const f32x4*)(bs + mt * 16 + 4 * g);

#pragma unroll
  for (int mt = 0; mt < 16; ++mt)
#pragma unroll
    for (int s = 0; s < 2; ++s) {
      bf16x8 kf = *(const bf16x8*)(khs + kswz(mt * 16 + lr, s * 32 + g * 8));
      acc[mt] = __builtin_amdgcn_mfma_f32_16x16x32_bf16(kf, qb[s], acc[mt], 0, 0, 0);
    }

  // ---- full-row softmax (log2 domain) ----
  float m = -1e38f;
#pragma unroll
  for (int mt = 0; mt < 16; ++mt) {
    m = max3f(acc[mt][0], acc[mt][1], m);
    m = max3f(acc[mt][2], acc[mt][3], m);
  }
  m = fmaxf(m, __shfl_xor(m, 16));
  m = fmaxf(m, __shfl_xor(m, 32));

  float l = 0.f;
#pragma unroll
  for (int mt = 0; mt < 16; ++mt)
#pragma unroll
    for (int r = 0; r < 4; ++r) {
      float p = exp2_hw(acc[mt][r] - m);
      acc[mt][r] = p;
      l += p;
    }
  l += __shfl_xor(l, 16);
  l += __shfl_xor(l, 32);
  const float inv = 1.f / l;

  // ---- NOW consume V (compiler waits its vmcnt here) + write V^T ----
  {
    const int c16v = ((kb >> 5) << 2) | ((kb >> 2) & 3);
    const int hiv = ((kb >> 4) & 1) << 2;          // u16 offset within chunk
#pragma unroll
    for (int h = 0; h < 2; ++h)
#pragma unroll
      for (int e = 0; e < 4; ++e) {
        int d = dg + h * 4 + e;
        u32x2 ww;
        ww.x = cvt_pk_bf16(va[0][h][e], va[1][h][e]);   // keys kb, kb+1
        ww.y = cvt_pk_bf16(va[2][h][e], va[3][h][e]);   // keys kb+2, kb+3
        *(u32x2*)(vts + (d << 8) + (cswz(d, c16v) << 3) + hiv) = ww;
      }
  }

  lds_barrier();   // barrier 2: vts visible

  // ---- PV: out = P * V.  A = P (regs, natural layout), B = V^T via single
  // b128 per (c,dt): chunk (4c+g) ^ swz at row d holds keys in jj order.
  f32x4 oacc[4];
#pragma unroll
  for (int dt = 0; dt < 4; ++dt)
    oacc[dt] = (f32x4){0.f, 0.f, 0.f, 0.f};

#pragma unroll
  for (int c = 0; c < 8; ++c) {
    union { unsigned w[4]; bf16x8 v; } pa;
    pa.w[0] = cvt_pk_bf16(acc[2 * c][0], acc[2 * c][1]);
    pa.w[1] = cvt_pk_bf16(acc[2 * c][2], acc[2 * c][3]);
    pa.w[2] = cvt_pk_bf16(acc[2 * c + 1][0], acc[2 * c + 1][1]);
    pa.w[3] = cvt_pk_bf16(acc[2 * c + 1][2], acc[2 * c + 1][3]);
#pragma unroll
    for (int dt = 0; dt < 4; ++dt) {
      int d = dt * 16 + lr;
      bf16x8 vb = *(const bf16x8*)(vts + (d << 8) + (cswz(d, 4 * c + g) << 3));
      oacc[dt] = __builtin_amdgcn_mfma_f32_16x16x32_bf16(pa.v, vb,
                                                         oacc[dt], 0, 0, 0);
    }
  }

  // ---- epilogue: C layout -> row = 4g + r (local), col = dt*16 + lr ----
  float* Ob = Og + base + (size_t)qrow0 * DD;
#pragma unroll
  for (int r = 0; r < 4; ++r) {
    float iv = __shfl(inv, 4 * g + r);      // lane 4g+r holds q = 4g+r
    int row = 4 * g + r;
#pragma unroll
    for (int dt = 0; dt < 4; ++dt)
      Ob[(size_t)row * DD + dt * 16 + lr] = oacc[dt][r] * iv;
  }
}

extern "C" void kernel_launch(void* const* d_in, const int* in_sizes, int n_in,
                              void* d_out, int out_size, void* d_ws, size_t ws_size,
                              hipStream_t stream) {
  (void)in_sizes; (void)n_in; (void)out_size; (void)d_ws; (void)ws_size;
  const float* Q = (const float*)d_in[0];
  const float* K = (const float*)d_in[1];
  const float* V = (const float*)d_in[2];
  const float* M = (const float*)d_in[3];
  float* O = (float*)d_out;

  hipLaunchKernelGGL(swa_fwd, dim3(NB * NH * 32), dim3(512), 0, stream,
                     Q, K, V, M, O);
}

// Round 20
// 50.585 us; speedup vs baseline: 1.1283x; 1.1283x over previous
//
#include <hip/hip_runtime.h>

typedef float f32x4 __attribute__((ext_vector_type(4)));
typedef __bf16 bf16x8 __attribute__((ext_vector_type(8)));
typedef unsigned short u16x8 __attribute__((ext_vector_type(8)));

#define NB 4
#define NH 16
#define TT 4096
#define DD 64
#define LOG2E 1.4426950408889634f
#define QSCALE (LOG2E * 0.125f)   // (1/sqrt(64)) * log2(e)
#define NEGB (-1.5e9f)            // large-negative (log2 domain); exp2 -> 0

__device__ __forceinline__ unsigned cvt_pk_bf16(float a, float b) {
  unsigned r;
  asm("v_cvt_pk_bf16_f32 %0, %1, %2" : "=v"(r) : "v"(a), "v"(b));
  return r;   // lo16 = bf16(a), hi16 = bf16(b)  (RNE)
}
__device__ __forceinline__ float exp2_hw(float x) {
  float r;
  asm("v_exp_f32 %0, %1" : "=v"(r) : "v"(x));
  return r;
}
__device__ __forceinline__ float max3f(float a, float b, float c) {
  float r;
  asm("v_max3_f32 %0, %1, %2, %3" : "=v"(r) : "v"(a), "v"(b), "v"(c));
  return r;
}

// Barrier that waits ONLY on LDS (lgkmcnt), NOT on outstanding global loads.
// No sched_barrier fences: the "memory" clobber orders LDS ops; ds_read->MFMA
// dependencies are compiler-tracked.
__device__ __forceinline__ void lds_barrier() {
  asm volatile("s_waitcnt lgkmcnt(0)" ::: "memory");
  __builtin_amdgcn_s_barrier();
}

// K tile [256][64] u16 row-major, XOR swizzle for b128 reads at row-stride 128B.
__device__ __forceinline__ int kswz(int key, int d) {
  return ((key << 6) + d) ^ ((key & 7) << 3);
}
// V^T tile [64][256] u16, slot-permuted within 32-key chunks so one lane's 8
// PV-B keys {32c+16hi+4g+r} are ONE contiguous 16B chunk in jj=r+4*hi order:
//   u16 slot within chunk = (key&3) | ((key>>4)&1)<<2
//   16B-chunk index c16(key) = (key>>5)*4 + ((key>>2)&3), swizzled by d.
__device__ __forceinline__ int cswz(int d, int c16) {
  return c16 ^ (d & 7) ^ ((d >> 3) & 7);
}

__global__ __launch_bounds__(512, 4) void swa_fwd(
    const float* __restrict__ Qg, const float* __restrict__ Kg,
    const float* __restrict__ Vg, const float* __restrict__ Mg,
    float* __restrict__ Og) {
  // 65.5 KiB static LDS -> 2 blocks/CU; 8 waves/block -> 4 waves/SIMD (128-reg cap).
  __shared__ unsigned short khs[256 * 64];   // 32 KiB  K  (bf16, kswz)
  __shared__ unsigned short vts[64 * 256];   // 32 KiB  V^T (bf16, slot+cswz)
  __shared__ float bs[256];                  // 1 KiB   bias (mask*log2e / NEGB)

  // XCD-bijective swizzle: 2048 blocks, 8 XCDs, contiguous work per XCD.
  const int bid = blockIdx.x;
  const int flat = (bid & 7) * 256 + (bid >> 3);
  const int i = flat & 31;        // q-block
  const int bh = flat >> 5;       // b*NH + h
  const int b = bh >> 4;

  const int t = threadIdx.x;      // 0..511
  const int lane = t & 63;
  const int wid = t >> 6;         // 0..7
  const int lr = lane & 15;
  const int g = lane >> 4;

  const size_t base = (size_t)bh * (TT * DD);
  const float* Qb = Qg + base;
  const float* Kb = Kg + base;
  const float* Vb = Vg + base;
  const float* Mb = Mg + (size_t)b * TT;
  const int j0 = i * 128 - 128;           // window start (may be -128 for i==0)
  const int qrow0 = i * 128 + wid * 16;   // this wave's 16 rows

  const int dg = (t & 7) * 8;     // 8 consecutive d per thread
  const int rowt = t >> 3;        // K staging: 64 keys per iter
  const int kb = (t >> 3) * 4;    // V staging: 4 consecutive keys per thread

  // ---- issue order (vmcnt): K, Q, mask, V01, V23. All waves symmetric. ----
  f32x4 ka[4][2];
#pragma unroll
  for (int it = 0; it < 4; ++it) {
    int j = j0 + it * 64 + rowt;
    j = j < 0 ? 0 : j;            // clamp; invalid keys masked via bias later
    const float* ks = Kb + (size_t)j * DD + dg;
    ka[it][0] = *(const f32x4*)ks;
    ka[it][1] = *(const f32x4*)(ks + 4);
  }
  f32x4 qraw[2][2];
#pragma unroll
  for (int s = 0; s < 2; ++s) {
    const float* qp = Qb + (size_t)(qrow0 + lr) * DD + s * 32 + g * 8;
    qraw[s][0] = *(const f32x4*)qp;
    qraw[s][1] = *(const f32x4*)(qp + 4);
  }
  // mask row: ALL waves load the same 256 entries (4/lane), clamped address.
  const int jm = j0 + (lane << 2);
  const int jmc = jm < 0 ? 0 : jm;
  f32x4 mrow = *(const f32x4*)(Mb + jmc);
  // V halves issued LAST; consumed mid-QK (V01) and after softmax (V23).
  f32x4 va01[2][2], va23[2][2];
#pragma unroll
  for (int k = 0; k < 2; ++k) {
    int j = j0 + kb + k;
    j = j < 0 ? 0 : j;
    const float* vs = Vb + (size_t)j * DD + dg;
    va01[k][0] = *(const f32x4*)vs;
    va01[k][1] = *(const f32x4*)(vs + 4);
  }
#pragma unroll
  for (int k = 0; k < 2; ++k) {
    int j = j0 + kb + 2 + k;
    j = j < 0 ? 0 : j;
    const float* vs = Vb + (size_t)j * DD + dg;
    va23[k][0] = *(const f32x4*)vs;
    va23[k][1] = *(const f32x4*)(vs + 4);
  }

  // ---- convert + write K (b128, swizzled); waits only on K loads ----
#pragma unroll
  for (int it = 0; it < 4; ++it) {
    int key = it * 64 + rowt;
    union { u16x8 v; unsigned w[4]; } hh;
    hh.w[0] = cvt_pk_bf16(ka[it][0][0], ka[it][0][1]);
    hh.w[1] = cvt_pk_bf16(ka[it][0][2], ka[it][0][3]);
    hh.w[2] = cvt_pk_bf16(ka[it][1][0], ka[it][1][1]);
    hh.w[3] = cvt_pk_bf16(ka[it][1][2], ka[it][1][3]);
    *(u16x8*)(khs + kswz(key, dg)) = hh.v;
  }

  // ---- bias commit: ALL waves write identical values (benign WW race) ----
  {
    f32x4 bb;
    if (jm >= 0) {
      bb = mrow * LOG2E;
    } else {
      bb = (f32x4){NEGB, NEGB, NEGB, NEGB};
    }
    *(f32x4*)(bs + (lane << 2)) = bb;
  }

  // ---- Q fragments: plain bf16 of q * (log2e/8) ----
  bf16x8 qb[2];
#pragma unroll
  for (int s = 0; s < 2; ++s) {
    union { unsigned w[4]; bf16x8 v; } H;
    H.w[0] = cvt_pk_bf16(qraw[s][0][0] * QSCALE, qraw[s][0][1] * QSCALE);
    H.w[1] = cvt_pk_bf16(qraw[s][0][2] * QSCALE, qraw[s][0][3] * QSCALE);
    H.w[2] = cvt_pk_bf16(qraw[s][1][0] * QSCALE, qraw[s][1][1] * QSCALE);
    H.w[3] = cvt_pk_bf16(qraw[s][1][2] * QSCALE, qraw[s][1][3] * QSCALE);
    qb[s] = H.v;
  }

  lds_barrier();   // barrier 1: khs + bias visible; V loads STILL IN FLIGHT

  // ---- QK: acc preloaded with bias; S^T = K * Q^T accumulates on top. ----
  // lane value (mt,r): key = mt*16 + 4g + r ; qrow = lr
  f32x4 acc[16];
#pragma unroll
  for (int mt = 0; mt < 16; ++mt)
    acc[mt] = *(const f32x4*)(bs + mt * 16 + 4 * g);

  const int c16v = ((kb >> 5) << 2) | ((kb >> 2) & 3);
  const int hiv = ((kb >> 4) & 1) << 2;            // u16 offset within chunk

#pragma unroll
  for (int mt = 0; mt < 8; ++mt)
#pragma unroll
    for (int s = 0; s < 2; ++s) {
      bf16x8 kf = *(const bf16x8*)(khs + kswz(mt * 16 + lr, s * 32 + g * 8));
      acc[mt] = __builtin_amdgcn_mfma_f32_16x16x32_bf16(kf, qb[s], acc[mt], 0, 0, 0);
    }

  // ---- consume V01 (keys kb, kb+1): latency hidden under QK half 1 ----
#pragma unroll
  for (int h = 0; h < 2; ++h)
#pragma unroll
    for (int e = 0; e < 4; ++e) {
      int d = dg + h * 4 + e;
      unsigned ww = cvt_pk_bf16(va01[0][h][e], va01[1][h][e]);
      *(unsigned*)(vts + (d << 8) + (cswz(d, c16v) << 3) + hiv) = ww;
    }

#pragma unroll
  for (int mt = 8; mt < 16; ++mt)
#pragma unroll
    for (int s = 0; s < 2; ++s) {
      bf16x8 kf = *(const bf16x8*)(khs + kswz(mt * 16 + lr, s * 32 + g * 8));
      acc[mt] = __builtin_amdgcn_mfma_f32_16x16x32_bf16(kf, qb[s], acc[mt], 0, 0, 0);
    }

  // ---- full-row softmax (log2 domain) ----
  float m = -1e38f;
#pragma unroll
  for (int mt = 0; mt < 16; ++mt) {
    m = max3f(acc[mt][0], acc[mt][1], m);
    m = max3f(acc[mt][2], acc[mt][3], m);
  }
  m = fmaxf(m, __shfl_xor(m, 16));
  m = fmaxf(m, __shfl_xor(m, 32));

  float l = 0.f;
#pragma unroll
  for (int mt = 0; mt < 16; ++mt)
#pragma unroll
    for (int r = 0; r < 4; ++r) {
      float p = exp2_hw(acc[mt][r] - m);
      acc[mt][r] = p;
      l += p;
    }
  l += __shfl_xor(l, 16);
  l += __shfl_xor(l, 32);
  const float inv = 1.f / l;

  // ---- consume V23 (keys kb+2, kb+3): latency hidden under QK2+softmax ----
#pragma unroll
  for (int h = 0; h < 2; ++h)
#pragma unroll
    for (int e = 0; e < 4; ++e) {
      int d = dg + h * 4 + e;
      unsigned ww = cvt_pk_bf16(va23[0][h][e], va23[1][h][e]);
      *(unsigned*)(vts + (d << 8) + (cswz(d, c16v) << 3) + hiv + 2) = ww;
    }

  lds_barrier();   // barrier 2: vts visible

  // ---- PV: out = P * V.  A = P (regs, natural layout), B = V^T via single
  // b128 per (c,dt): chunk (4c+g) ^ swz at row d holds keys in jj order.
  f32x4 oacc[4];
#pragma unroll
  for (int dt = 0; dt < 4; ++dt)
    oacc[dt] = (f32x4){0.f, 0.f, 0.f, 0.f};

#pragma unroll
  for (int c = 0; c < 8; ++c) {
    union { unsigned w[4]; bf16x8 v; } pa;
    pa.w[0] = cvt_pk_bf16(acc[2 * c][0], acc[2 * c][1]);
    pa.w[1] = cvt_pk_bf16(acc[2 * c][2], acc[2 * c][3]);
    pa.w[2] = cvt_pk_bf16(acc[2 * c + 1][0], acc[2 * c + 1][1]);
    pa.w[3] = cvt_pk_bf16(acc[2 * c + 1][2], acc[2 * c + 1][3]);
#pragma unroll
    for (int dt = 0; dt < 4; ++dt) {
      int d = dt * 16 + lr;
      bf16x8 vb = *(const bf16x8*)(vts + (d << 8) + (cswz(d, 4 * c + g) << 3));
      oacc[dt] = __builtin_amdgcn_mfma_f32_16x16x32_bf16(pa.v, vb,
                                                         oacc[dt], 0, 0, 0);
    }
  }

  // ---- epilogue: C layout -> row = 4g + r (local), col = dt*16 + lr ----
  float* Ob = Og + base + (size_t)qrow0 * DD;
#pragma unroll
  for (int r = 0; r < 4; ++r) {
    float iv = __shfl(inv, 4 * g + r);      // lane 4g+r holds q = 4g+r
    int row = 4 * g + r;
#pragma unroll
    for (int dt = 0; dt < 4; ++dt)
      Ob[(size_t)row * DD + dt * 16 + lr] = oacc[dt][r] * iv;
  }
}

extern "C" void kernel_launch(void* const* d_in, const int* in_sizes, int n_in,
                              void* d_out, int out_size, void* d_ws, size_t ws_size,
                              hipStream_t stream) {
  (void)in_sizes; (void)n_in; (void)out_size; (void)d_ws; (void)ws_size;
  const float* Q = (const float*)d_in[0];
  const float* K = (const float*)d_in[1];
  const float* V = (const float*)d_in[2];
  const float* M = (const float*)d_in[3];
  float* O = (float*)d_out;

  hipLaunchKernelGGL(swa_fwd, dim3(NB * NH * 32), dim3(512), 0, stream,
                     Q, K, V, M, O);
}

// Round 21
// 50.545 us; speedup vs baseline: 1.1292x; 1.0008x over previous
//
#include <hip/hip_runtime.h>

typedef float f32x4 __attribute__((ext_vector_type(4)));
typedef __bf16 bf16x8 __attribute__((ext_vector_type(8)));
typedef unsigned short u16x8 __attribute__((ext_vector_type(8)));

#define NB 4
#define NH 16
#define TT 4096
#define DD 64
#define LOG2E 1.4426950408889634f
#define QSCALE (LOG2E * 0.125f)   // (1/sqrt(64)) * log2(e)
#define NEGB (-1.5e9f)            // large-negative (log2 domain); exp2 -> 0

__device__ __forceinline__ unsigned cvt_pk_bf16(float a, float b) {
  unsigned r;
  asm("v_cvt_pk_bf16_f32 %0, %1, %2" : "=v"(r) : "v"(a), "v"(b));
  return r;   // lo16 = bf16(a), hi16 = bf16(b)  (RNE)
}
__device__ __forceinline__ float exp2_hw(float x) {
  float r;
  asm("v_exp_f32 %0, %1" : "=v"(r) : "v"(x));
  return r;
}
__device__ __forceinline__ float max3f(float a, float b, float c) {
  float r;
  asm("v_max3_f32 %0, %1, %2, %3" : "=v"(r) : "v"(a), "v"(b), "v"(c));
  return r;
}

// Barrier that waits ONLY on LDS (lgkmcnt), NOT on outstanding global loads.
__device__ __forceinline__ void lds_barrier() {
  asm volatile("s_waitcnt lgkmcnt(0)" ::: "memory");
  __builtin_amdgcn_s_barrier();
}

// K tile [256][64] u16 row-major, XOR swizzle for b128 reads at row-stride 128B.
__device__ __forceinline__ int kswz(int key, int d) {
  return ((key << 6) + d) ^ ((key & 7) << 3);
}
// V^T tile [64][256] u16, slot-permuted within 32-key chunks so one lane's 8
// PV-B keys {32c+16hi+4g+r} are ONE contiguous 16B chunk in jj=r+4*hi order:
//   u16 slot within chunk = (key&3) | ((key>>4)&1)<<2
//   16B-chunk index c16(key) = (key>>5)*4 + ((key>>2)&3), swizzled by d.
__device__ __forceinline__ int cswz(int d, int c16) {
  return c16 ^ (d & 7) ^ ((d >> 3) & 7);
}

__global__ __launch_bounds__(512, 4) void swa_fwd(
    const float* __restrict__ Qg, const float* __restrict__ Kg,
    const float* __restrict__ Vg, const float* __restrict__ Mg,
    float* __restrict__ Og) {
  // 65.5 KiB static LDS -> 2 blocks/CU; 8 waves/block -> 4 waves/SIMD (128-reg cap).
  __shared__ unsigned short khs[256 * 64];   // 32 KiB  K  (bf16, kswz)
  __shared__ unsigned short vts[64 * 256];   // 32 KiB  V^T (bf16, slot+cswz)
  __shared__ float bs[256];                  // 1 KiB   bias (mask*log2e / NEGB)

  // XCD-bijective swizzle: 2048 blocks, 8 XCDs, contiguous work per XCD.
  const int bid = blockIdx.x;
  const int flat = (bid & 7) * 256 + (bid >> 3);
  const int i = flat & 31;        // q-block
  const int bh = flat >> 5;       // b*NH + h
  const int b = bh >> 4;

  const int t = threadIdx.x;      // 0..511
  const int lane = t & 63;
  const int wid = t >> 6;         // 0..7
  const int lr = lane & 15;
  const int g = lane >> 4;

  const size_t base = (size_t)bh * (TT * DD);
  const float* Qb = Qg + base;
  const float* Kb = Kg + base;
  const float* Vb = Vg + base;
  const float* Mb = Mg + (size_t)b * TT;
  const int j0 = i * 128 - 128;           // window start (may be -128 for i==0)
  const int qrow0 = i * 128 + wid * 16;   // this wave's 16 rows

  const int dg = (t & 7) * 8;     // 8 consecutive d per thread
  const int rowt = t >> 3;        // K staging: 64 keys per iter
  const int kb = (t >> 3) * 4;    // V staging: 4 consecutive keys per thread

  // ---- issue order (vmcnt): K, Q, mask, V01, V23. All waves symmetric. ----
  f32x4 ka[4][2];
#pragma unroll
  for (int it = 0; it < 4; ++it) {
    int j = j0 + it * 64 + rowt;
    j = j < 0 ? 0 : j;            // clamp; invalid keys masked via bias later
    const float* ks = Kb + (size_t)j * DD + dg;
    ka[it][0] = *(const f32x4*)ks;
    ka[it][1] = *(const f32x4*)(ks + 4);
  }
  f32x4 qraw[2][2];
#pragma unroll
  for (int s = 0; s < 2; ++s) {
    const float* qp = Qb + (size_t)(qrow0 + lr) * DD + s * 32 + g * 8;
    qraw[s][0] = *(const f32x4*)qp;
    qraw[s][1] = *(const f32x4*)(qp + 4);
  }
  // mask row: ALL waves load the same 256 entries (4/lane), clamped address.
  const int jm = j0 + (lane << 2);
  const int jmc = jm < 0 ? 0 : jm;
  f32x4 mrow = *(const f32x4*)(Mb + jmc);
  // V halves issued LAST; consumed mid-QK (V01) and right after QK (V23).
  f32x4 va01[2][2], va23[2][2];
#pragma unroll
  for (int k = 0; k < 2; ++k) {
    int j = j0 + kb + k;
    j = j < 0 ? 0 : j;
    const float* vs = Vb + (size_t)j * DD + dg;
    va01[k][0] = *(const f32x4*)vs;
    va01[k][1] = *(const f32x4*)(vs + 4);
  }
#pragma unroll
  for (int k = 0; k < 2; ++k) {
    int j = j0 + kb + 2 + k;
    j = j < 0 ? 0 : j;
    const float* vs = Vb + (size_t)j * DD + dg;
    va23[k][0] = *(const f32x4*)vs;
    va23[k][1] = *(const f32x4*)(vs + 4);
  }

  // ---- convert + write K (b128, swizzled); waits only on K loads ----
#pragma unroll
  for (int it = 0; it < 4; ++it) {
    int key = it * 64 + rowt;
    union { u16x8 v; unsigned w[4]; } hh;
    hh.w[0] = cvt_pk_bf16(ka[it][0][0], ka[it][0][1]);
    hh.w[1] = cvt_pk_bf16(ka[it][0][2], ka[it][0][3]);
    hh.w[2] = cvt_pk_bf16(ka[it][1][0], ka[it][1][1]);
    hh.w[3] = cvt_pk_bf16(ka[it][1][2], ka[it][1][3]);
    *(u16x8*)(khs + kswz(key, dg)) = hh.v;
  }

  // ---- bias commit: ALL waves write identical values (benign WW race) ----
  {
    f32x4 bb;
    if (jm >= 0) {
      bb = mrow * LOG2E;
    } else {
      bb = (f32x4){NEGB, NEGB, NEGB, NEGB};
    }
    *(f32x4*)(bs + (lane << 2)) = bb;
  }

  // ---- Q fragments: plain bf16 of q * (log2e/8) ----
  bf16x8 qb[2];
#pragma unroll
  for (int s = 0; s < 2; ++s) {
    union { unsigned w[4]; bf16x8 v; } H;
    H.w[0] = cvt_pk_bf16(qraw[s][0][0] * QSCALE, qraw[s][0][1] * QSCALE);
    H.w[1] = cvt_pk_bf16(qraw[s][0][2] * QSCALE, qraw[s][0][3] * QSCALE);
    H.w[2] = cvt_pk_bf16(qraw[s][1][0] * QSCALE, qraw[s][1][1] * QSCALE);
    H.w[3] = cvt_pk_bf16(qraw[s][1][2] * QSCALE, qraw[s][1][3] * QSCALE);
    qb[s] = H.v;
  }

  lds_barrier();   // barrier 1: khs + bias visible; V loads STILL IN FLIGHT

  // ---- QK: acc preloaded with bias; S^T = K * Q^T accumulates on top. ----
  // lane value (mt,r): key = mt*16 + 4g + r ; qrow = lr
  f32x4 acc[16];
#pragma unroll
  for (int mt = 0; mt < 16; ++mt)
    acc[mt] = *(const f32x4*)(bs + mt * 16 + 4 * g);

  const int c16v = ((kb >> 5) << 2) | ((kb >> 2) & 3);
  const int hiv = ((kb >> 4) & 1) << 2;            // u16 offset within chunk

#pragma unroll
  for (int mt = 0; mt < 8; ++mt)
#pragma unroll
    for (int s = 0; s < 2; ++s) {
      bf16x8 kf = *(const bf16x8*)(khs + kswz(mt * 16 + lr, s * 32 + g * 8));
      acc[mt] = __builtin_amdgcn_mfma_f32_16x16x32_bf16(kf, qb[s], acc[mt], 0, 0, 0);
    }

  // ---- consume V01 (keys kb, kb+1): latency hidden under QK half 1 ----
#pragma unroll
  for (int h = 0; h < 2; ++h)
#pragma unroll
    for (int e = 0; e < 4; ++e) {
      int d = dg + h * 4 + e;
      unsigned ww = cvt_pk_bf16(va01[0][h][e], va01[1][h][e]);
      *(unsigned*)(vts + (d << 8) + (cswz(d, c16v) << 3) + hiv) = ww;
    }

#pragma unroll
  for (int mt = 8; mt < 16; ++mt)
#pragma unroll
    for (int s = 0; s < 2; ++s) {
      bf16x8 kf = *(const bf16x8*)(khs + kswz(mt * 16 + lr, s * 32 + g * 8));
      acc[mt] = __builtin_amdgcn_mfma_f32_16x16x32_bf16(kf, qb[s], acc[mt], 0, 0, 0);
    }

  // ---- consume V23 (keys kb+2, kb+3): latency hidden under QK half 2 ----
#pragma unroll
  for (int h = 0; h < 2; ++h)
#pragma unroll
    for (int e = 0; e < 4; ++e) {
      int d = dg + h * 4 + e;
      unsigned ww = cvt_pk_bf16(va23[0][h][e], va23[1][h][e]);
      *(unsigned*)(vts + (d << 8) + (cswz(d, c16v) << 3) + hiv + 2) = ww;
    }

  lds_barrier();   // barrier 2: vts visible (before softmax -> PV can fuse)

  // ---- row max (log2 domain): serial VALU, needs all 64 scores ----
  float m = -1e38f;
#pragma unroll
  for (int mt = 0; mt < 16; ++mt) {
    m = max3f(acc[mt][0], acc[mt][1], m);
    m = max3f(acc[mt][2], acc[mt][3], m);
  }
  m = fmaxf(m, __shfl_xor(m, 16));
  m = fmaxf(m, __shfl_xor(m, 32));

  // ---- FUSED exp + pack + PV per 32-key chunk: VALU (exp2/cvt) of chunk c+1
  // overlaps MFMA+LDS of chunk c (no cross-chunk dependence except oacc chain).
  float l = 0.f;
  f32x4 oacc[4];
#pragma unroll
  for (int dt = 0; dt < 4; ++dt)
    oacc[dt] = (f32x4){0.f, 0.f, 0.f, 0.f};

#pragma unroll
  for (int c = 0; c < 8; ++c) {
    float p0 = exp2_hw(acc[2 * c][0] - m);
    float p1 = exp2_hw(acc[2 * c][1] - m);
    float p2 = exp2_hw(acc[2 * c][2] - m);
    float p3 = exp2_hw(acc[2 * c][3] - m);
    float p4 = exp2_hw(acc[2 * c + 1][0] - m);
    float p5 = exp2_hw(acc[2 * c + 1][1] - m);
    float p6 = exp2_hw(acc[2 * c + 1][2] - m);
    float p7 = exp2_hw(acc[2 * c + 1][3] - m);
    l += (p0 + p1) + (p2 + p3) + ((p4 + p5) + (p6 + p7));
    union { unsigned w[4]; bf16x8 v; } pa;
    pa.w[0] = cvt_pk_bf16(p0, p1);
    pa.w[1] = cvt_pk_bf16(p2, p3);
    pa.w[2] = cvt_pk_bf16(p4, p5);
    pa.w[3] = cvt_pk_bf16(p6, p7);
#pragma unroll
    for (int dt = 0; dt < 4; ++dt) {
      int d = dt * 16 + lr;
      bf16x8 vb = *(const bf16x8*)(vts + (d << 8) + (cswz(d, 4 * c + g) << 3));
      oacc[dt] = __builtin_amdgcn_mfma_f32_16x16x32_bf16(pa.v, vb,
                                                         oacc[dt], 0, 0, 0);
    }
  }

  l += __shfl_xor(l, 16);
  l += __shfl_xor(l, 32);
  const float inv = 1.f / l;

  // ---- epilogue: C layout -> row = 4g + r (local), col = dt*16 + lr ----
  float* Ob = Og + base + (size_t)qrow0 * DD;
#pragma unroll
  for (int r = 0; r < 4; ++r) {
    float iv = __shfl(inv, 4 * g + r);      // lane 4g+r holds q = 4g+r
    int row = 4 * g + r;
#pragma unroll
    for (int dt = 0; dt < 4; ++dt)
      Ob[(size_t)row * DD + dt * 16 + lr] = oacc[dt][r] * iv;
  }
}

extern "C" void kernel_launch(void* const* d_in, const int* in_sizes, int n_in,
                              void* d_out, int out_size, void* d_ws, size_t ws_size,
                              hipStream_t stream) {
  (void)in_sizes; (void)n_in; (void)out_size; (void)d_ws; (void)ws_size;
  const float* Q = (const float*)d_in[0];
  const float* K = (const float*)d_in[1];
  const float* V = (const float*)d_in[2];
  const float* M = (const float*)d_in[3];
  float* O = (float*)d_out;

  hipLaunchKernelGGL(swa_fwd, dim3(NB * NH * 32), dim3(512), 0, stream,
                     Q, K, V, M, O);
}